// Round 1
// baseline (673.425 us; speedup 1.0000x reference)
//
#include <hip/hip_runtime.h>
#include <math.h>

#define B_  8
#define S_  8192
#define D_  64
#define H_  8
#define NB_ 128     // buckets per hash round
#define NC_ 1024    // chunks per batch (H_*NB_)

// ---------------------------------------------------------------------------
// Kernel 1: LSH hash. rotated[b,h,t,i] = sum_f qk[b,t,f]*rot[f,h,i] (fp64 acc),
// bucket = argmax over concat([r, -r]) with numpy first-max semantics.
// ---------------------------------------------------------------------------
__global__ __launch_bounds__(256) void hash_kernel(
    const float* __restrict__ qk, const float* __restrict__ rot,
    int* __restrict__ bucket)
{
  __shared__ double rotT[64 * 64];            // [f][i], fp64, 32 KB
  const int tid  = threadIdx.x;
  const int tile = blockIdx.x & 31;           // 32 tiles of 256 tokens
  const int bh   = blockIdx.x >> 5;           // b*8 + h
  const int h    = bh & 7;
  const int b    = bh >> 3;

  {                                           // load rot slice for this h
    const int f = tid >> 2, q = tid & 3;
    const float* src = rot + f * 512 + h * 64 + q * 16;  // rot[f][h][i]
    double* dst = rotT + f * 64 + q * 16;
#pragma unroll
    for (int k = 0; k < 16; ++k) dst[k] = (double)src[k];
  }
  __syncthreads();

  const int t = tile * 256 + tid;
  const float* qrow = qk + ((size_t)b * S_ + t) * D_;
  float q[64];
#pragma unroll
  for (int k = 0; k < 16; ++k) ((float4*)q)[k] = ((const float4*)qrow)[k];

  double best_max = -1e300, best_min = 1e300;
  int arg_max = 0, arg_min = 0;
#pragma unroll 1
  for (int i0 = 0; i0 < 64; i0 += 8) {
    double acc[8];
#pragma unroll
    for (int a = 0; a < 8; ++a) acc[a] = 0.0;
    for (int f = 0; f < 64; ++f) {
      const double qd = (double)q[f];
      const double* rp = rotT + f * 64 + i0;  // wave-uniform -> LDS broadcast
#pragma unroll
      for (int a = 0; a < 8; ++a) acc[a] = fma(qd, rp[a], acc[a]);
    }
#pragma unroll
    for (int a = 0; a < 8; ++a) {             // strict compares keep FIRST max/min
      const double x = acc[a];
      if (x > best_max) { best_max = x; arg_max = i0 + a; }
      if (x < best_min) { best_min = x; arg_min = i0 + a; }
    }
  }
  // argmax([r, -r]): tie (max == -min) picks the r side (lower index) -> >=
  const int bkt = (best_max >= -best_min) ? arg_max : 64 + arg_min;
  bucket[(size_t)bh * S_ + t] = bkt;
}

// ---------------------------------------------------------------------------
// Kernel 2: stable counting sort per (b,h): 8192 tokens into 128 buckets,
// stable by token id. Emits st[b][h*S+p] = token, undo[b][h][t] = h*S + p.
// ---------------------------------------------------------------------------
__global__ __launch_bounds__(1024) void sort_kernel(
    const int* __restrict__ bucket, int* __restrict__ st,
    int* __restrict__ undo)
{
  __shared__ int lb[S_];                      // 32 KB
  __shared__ int hist[8 * 128];               // [seg][bkt]
  __shared__ int off[128];
  const int tid = threadIdx.x;
  const int bh  = blockIdx.x;                 // b*8 + h
  const size_t base = (size_t)bh * S_;

  for (int k = tid; k < S_; k += 1024) lb[k] = bucket[base + k];
  hist[tid] = 0;
  __syncthreads();

  {                                           // per-segment histogram
    const int seg = tid >> 7;                 // token t belongs to seg t>>10
    const int t0 = tid * 8;
#pragma unroll
    for (int k = 0; k < 8; ++k) atomicAdd(&hist[seg * 128 + lb[t0 + k]], 1);
  }
  __syncthreads();
  if (tid < 128) {                            // bucket totals
    int s = 0;
#pragma unroll
    for (int g = 0; g < 8; ++g) s += hist[g * 128 + tid];
    off[tid] = s;
  }
  __syncthreads();
  if (tid == 0) {                             // exclusive prefix over buckets
    int run = 0;
    for (int k = 0; k < 128; ++k) { const int c = off[k]; off[k] = run; run += c; }
  }
  __syncthreads();
  if (tid < 128) {                            // per-(seg,bucket) start offsets
    int run = off[tid];
#pragma unroll
    for (int g = 0; g < 8; ++g) { const int c = hist[g * 128 + tid]; hist[g * 128 + tid] = run; run += c; }
  }
  __syncthreads();

  const int bkt = tid & 127;
  const int seg = tid >> 7;
  int pos = hist[seg * 128 + bkt];
  const int sbase = seg * 1024;
  const int b = bh >> 3, h = bh & 7;
  const size_t stb = (size_t)b * (H_ * S_) + (size_t)h * S_;
  for (int k = 0; k < 1024; ++k) {
    const int t = sbase + k;                  // lb[t] is a wave-broadcast read
    if (lb[t] == bkt) {
      st[stb + pos] = t;
      undo[base + t] = h * S_ + pos;
      ++pos;
    }
  }
}

// ---------------------------------------------------------------------------
// Kernel 3: bucketed attention. One block per (b, chunk c). 64 q x 128 kv x 64d.
// LDS exactly 64 KB: R2 = kT[64f][128j] -> dots/p[128j][64i]; R1 = ids/norms -> v.
// ---------------------------------------------------------------------------
__global__ __launch_bounds__(256) void attn_kernel(
    const float* __restrict__ qk, const float* __restrict__ v,
    const int* __restrict__ st, float* __restrict__ so,
    float* __restrict__ slogits)
{
  __shared__ float R1[8192];                  // 32 KB
  __shared__ float R2[8192];                  // 32 KB
  const int tid = threadIdx.x;
  const int c   = blockIdx.x & (NC_ - 1);
  const int b   = blockIdx.x >> 10;
  const int cm1 = (c + NC_ - 1) & (NC_ - 1);  // look-one-back, wraps per batch
  const size_t bst = (size_t)b * (H_ * S_);

  int*   ktL  = (int*)R1;                     // [128] kv token ids
  float* invL = R1 + 128;                     // [128] 0.125/(||k||+1e-6)

  if (tid < 128) {
    const int j = tid;
    ktL[j] = (j < 64) ? st[bst + (size_t)c * 64 + j]
                      : st[bst + (size_t)cm1 * 64 + (j - 64)];
  }
  {                                           // stage kT (= q rows for j<64)
    const int r = tid >> 1, half = tid & 1;
    const int tok = (r < 64) ? st[bst + (size_t)c * 64 + r]
                             : st[bst + (size_t)cm1 * 64 + (r - 64)];
    const float4* src = (const float4*)(qk + ((size_t)b * S_ + tok) * D_ + half * 32);
#pragma unroll
    for (int k = 0; k < 8; ++k) {
      const float4 x = src[k];
      const int f = half * 32 + k * 4;
      R2[(f + 0) * 128 + r] = x.x;
      R2[(f + 1) * 128 + r] = x.y;
      R2[(f + 2) * 128 + r] = x.z;
      R2[(f + 3) * 128 + r] = x.w;
    }
  }
  __syncthreads();                            // barrier0: kT + ids ready

  if (tid < 128) {                            // key norms
    float s = 0.f;
#pragma unroll
    for (int f = 0; f < 64; ++f) { const float x = R2[f * 128 + tid]; s = fmaf(x, x, s); }
    invL[tid] = 0.125f / (sqrtf(s) + 1e-6f);  // D^-0.5 folded in
  }

  // ---- QK^T: thread tile 8i x 4j ----
  const int ti = tid & 7;
  const int i0 = ti * 8;
  const int j0 = (tid >> 3) * 4;
  float acc[8][4];
#pragma unroll
  for (int a = 0; a < 8; ++a)
#pragma unroll
    for (int e = 0; e < 4; ++e) acc[a][e] = 0.f;

  for (int f = 0; f < 64; ++f) {
    const float4 qa = *(const float4*)(R2 + f * 128 + i0);
    const float4 qb = *(const float4*)(R2 + f * 128 + i0 + 4);
    const float4 kk = *(const float4*)(R2 + f * 128 + j0);
    const float qv[8] = {qa.x, qa.y, qa.z, qa.w, qb.x, qb.y, qb.z, qb.w};
    const float kv[4] = {kk.x, kk.y, kk.z, kk.w};
#pragma unroll
    for (int a = 0; a < 8; ++a)
#pragma unroll
      for (int e = 0; e < 4; ++e) acc[a][e] = fmaf(qv[a], kv[e], acc[a][e]);
  }
  __syncthreads();                            // barrier1: all kT reads done

  int kti[8], ktj[4]; float inv4[4];
#pragma unroll
  for (int a = 0; a < 8; ++a) kti[a] = ktL[i0 + a];
#pragma unroll
  for (int e = 0; e < 4; ++e) { ktj[e] = ktL[j0 + e]; inv4[e] = invL[j0 + e]; }
  const int rv = tid >> 1, halfv = tid & 1;
  const int tokv = ktL[rv];                   // capture before R1 is recycled

  // scale + self-mask, store dots transposed [j][i] into R2 (kT is dead)
#pragma unroll
  for (int e = 0; e < 4; ++e) {
    const int j = j0 + e;
    float f0[8];
#pragma unroll
    for (int a = 0; a < 8; ++a) {
      float x = acc[a][e] * inv4[e];
      if (kti[a] == ktj[e]) x = -5e4f;        // TOKEN_SELF_ATTN_VALUE
      f0[a] = x;
    }
    const float4 w0 = {f0[0], f0[1], f0[2], f0[3]};
    const float4 w1 = {f0[4], f0[5], f0[6], f0[7]};
    *(float4*)(R2 + j * 64 + i0)     = w0;
    *(float4*)(R2 + j * 64 + i0 + 4) = w1;
  }
  __syncthreads();                            // barrier2: dots stored, R1 free

  {                                           // stage v rows into R1
    const float4* srcv = (const float4*)(v + ((size_t)b * S_ + tokv) * D_ + halfv * 32);
    float4* dstv = (float4*)(R1 + rv * 64 + halfv * 32);
#pragma unroll
    for (int k = 0; k < 8; ++k) dstv[k] = srcv[k];
  }
  if (tid < 64) {                             // softmax per query row
    const int i = tid;
    float m = -1e30f;
    for (int j = 0; j < 128; ++j) m = fmaxf(m, R2[j * 64 + i]);
    float s = 0.f;
    for (int j = 0; j < 128; ++j) {
      const float e = expf(R2[j * 64 + i] - m);
      s += e;
      R2[j * 64 + i] = e;
    }
    const float is = 1.f / s;
    for (int j = 0; j < 128; ++j) R2[j * 64 + i] *= is;
    slogits[bst + (size_t)c * 64 + i] = m + logf(s);
  }
  __syncthreads();                            // barrier3: p + v ready

  // ---- PV: thread tile 8i x 2d ----
  const int d0 = (tid >> 3) * 2;
  float o0[8], o1[8];
#pragma unroll
  for (int a = 0; a < 8; ++a) { o0[a] = 0.f; o1[a] = 0.f; }
  for (int j = 0; j < 128; ++j) {
    const float4 pa = *(const float4*)(R2 + j * 64 + i0);
    const float4 pb = *(const float4*)(R2 + j * 64 + i0 + 4);
    const float2 vv = *(const float2*)(R1 + j * 64 + d0);
    const float pv[8] = {pa.x, pa.y, pa.z, pa.w, pb.x, pb.y, pb.z, pb.w};
#pragma unroll
    for (int a = 0; a < 8; ++a) {
      o0[a] = fmaf(pv[a], vv.x, o0[a]);
      o1[a] = fmaf(pv[a], vv.y, o1[a]);
    }
  }
  const size_t sob = bst + (size_t)c * 64;
#pragma unroll
  for (int a = 0; a < 8; ++a) {
    const float2 w = {o0[a], o1[a]};
    *(float2*)(so + (sob + i0 + a) * 64 + d0) = w;
  }
}

// ---------------------------------------------------------------------------
// Kernel 4: un-sort + combine rounds with logsumexp weights.
// ---------------------------------------------------------------------------
__global__ __launch_bounds__(256) void combine_kernel(
    const float* __restrict__ so, const float* __restrict__ slogits,
    const int* __restrict__ undo, float* __restrict__ out)
{
  const int gt = blockIdx.x * 4 + (threadIdx.x >> 6);   // (b,t) flat
  const int d  = threadIdx.x & 63;
  const int b  = gt >> 13;
  const int t  = gt & (S_ - 1);
  const size_t bst = (size_t)b * (H_ * S_);

  int p[8]; float l[8];
#pragma unroll
  for (int h = 0; h < 8; ++h) {
    p[h] = undo[((size_t)b * 8 + h) * S_ + t];
    l[h] = slogits[bst + p[h]];
  }
  float m = l[0];
#pragma unroll
  for (int h = 1; h < 8; ++h) m = fmaxf(m, l[h]);
  float w[8], W = 0.f;
#pragma unroll
  for (int h = 0; h < 8; ++h) { w[h] = expf(l[h] - m); W += w[h]; }
  const float iW = 1.f / W;
  float acc = 0.f;
#pragma unroll
  for (int h = 0; h < 8; ++h)
    acc = fmaf(w[h], so[(bst + (size_t)p[h]) * 64 + d], acc);
  out[(size_t)gt * 64 + d] = acc * iW;
}

// ---------------------------------------------------------------------------
extern "C" void kernel_launch(void* const* d_in, const int* in_sizes, int n_in,
                              void* d_out, int out_size, void* d_ws, size_t ws_size,
                              hipStream_t stream)
{
  const float* qk  = (const float*)d_in[0];
  const float* v   = (const float*)d_in[1];
  const float* rot = (const float*)d_in[2];
  float* out = (float*)d_out;

  char* ws = (char*)d_ws;
  const size_t MB = 1ull << 20;
  int*   bucket = (int*)  (ws + 0 * MB);      // B*H*S ints   = 2 MB
  int*   st     = (int*)  (ws + 2 * MB);      // B*H*S ints   = 2 MB
  int*   undo   = (int*)  (ws + 4 * MB);      // B*H*S ints   = 2 MB
  float* slog   = (float*)(ws + 6 * MB);      // B*H*S floats = 2 MB
  float* so     = (float*)(ws + 8 * MB);      // B*H*S*D floats = 128 MB
  if (ws_size < 136 * MB) return;             // need 136 MB of scratch

  hipLaunchKernelGGL(hash_kernel,    dim3(64 * 32),        dim3(256),  0, stream, qk, rot, bucket);
  hipLaunchKernelGGL(sort_kernel,    dim3(64),             dim3(1024), 0, stream, bucket, st, undo);
  hipLaunchKernelGGL(attn_kernel,    dim3(B_ * NC_),       dim3(256),  0, stream, qk, v, st, so, slog);
  hipLaunchKernelGGL(combine_kernel, dim3(B_ * S_ / 4),    dim3(256),  0, stream, so, slog, undo, out);
}

// Round 2
// 376.103 us; speedup vs baseline: 1.7905x; 1.7905x over previous
//
#include <hip/hip_runtime.h>
#include <math.h>

#define B_  8
#define S_  8192
#define D_  64
#define H_  8
#define NB_ 128     // buckets per hash round
#define NC_ 1024    // chunks per batch (H_*NB_)

typedef _Float16 f16x8 __attribute__((ext_vector_type(8)));
typedef _Float16 f16x2 __attribute__((ext_vector_type(2)));
typedef float    f32x4 __attribute__((ext_vector_type(4)));

// ---------------------------------------------------------------------------
// Kernel 1: LSH hash (fp64 accumulation -> argmax flips impossible). Unchanged.
// ---------------------------------------------------------------------------
__global__ __launch_bounds__(256) void hash_kernel(
    const float* __restrict__ qk, const float* __restrict__ rot,
    int* __restrict__ bucket)
{
  __shared__ double rotT[64 * 64];            // [f][i], fp64, 32 KB
  const int tid  = threadIdx.x;
  const int tile = blockIdx.x & 31;
  const int bh   = blockIdx.x >> 5;
  const int h    = bh & 7;
  const int b    = bh >> 3;

  {
    const int f = tid >> 2, q = tid & 3;
    const float* src = rot + f * 512 + h * 64 + q * 16;
    double* dst = rotT + f * 64 + q * 16;
#pragma unroll
    for (int k = 0; k < 16; ++k) dst[k] = (double)src[k];
  }
  __syncthreads();

  const int t = tile * 256 + tid;
  const float* qrow = qk + ((size_t)b * S_ + t) * D_;
  float q[64];
#pragma unroll
  for (int k = 0; k < 16; ++k) ((float4*)q)[k] = ((const float4*)qrow)[k];

  double best_max = -1e300, best_min = 1e300;
  int arg_max = 0, arg_min = 0;
#pragma unroll 1
  for (int i0 = 0; i0 < 64; i0 += 8) {
    double acc[8];
#pragma unroll
    for (int a = 0; a < 8; ++a) acc[a] = 0.0;
    for (int f = 0; f < 64; ++f) {
      const double qd = (double)q[f];
      const double* rp = rotT + f * 64 + i0;
#pragma unroll
      for (int a = 0; a < 8; ++a) acc[a] = fma(qd, rp[a], acc[a]);
    }
#pragma unroll
    for (int a = 0; a < 8; ++a) {
      const double x = acc[a];
      if (x > best_max) { best_max = x; arg_max = i0 + a; }
      if (x < best_min) { best_min = x; arg_min = i0 + a; }
    }
  }
  const int bkt = (best_max >= -best_min) ? arg_max : 64 + arg_min;
  bucket[(size_t)bh * S_ + t] = bkt;
}

// ---------------------------------------------------------------------------
// Kernel 2: stable counting sort per (b,h). Unchanged.
// ---------------------------------------------------------------------------
__global__ __launch_bounds__(1024) void sort_kernel(
    const int* __restrict__ bucket, int* __restrict__ st,
    int* __restrict__ undo)
{
  __shared__ int lb[S_];
  __shared__ int hist[8 * 128];
  __shared__ int off[128];
  const int tid = threadIdx.x;
  const int bh  = blockIdx.x;
  const size_t base = (size_t)bh * S_;

  for (int k = tid; k < S_; k += 1024) lb[k] = bucket[base + k];
  hist[tid] = 0;
  __syncthreads();

  {
    const int seg = tid >> 7;
    const int t0 = tid * 8;
#pragma unroll
    for (int k = 0; k < 8; ++k) atomicAdd(&hist[seg * 128 + lb[t0 + k]], 1);
  }
  __syncthreads();
  if (tid < 128) {
    int s = 0;
#pragma unroll
    for (int g = 0; g < 8; ++g) s += hist[g * 128 + tid];
    off[tid] = s;
  }
  __syncthreads();
  if (tid == 0) {
    int run = 0;
    for (int k = 0; k < 128; ++k) { const int c = off[k]; off[k] = run; run += c; }
  }
  __syncthreads();
  if (tid < 128) {
    int run = off[tid];
#pragma unroll
    for (int g = 0; g < 8; ++g) { const int c = hist[g * 128 + tid]; hist[g * 128 + tid] = run; run += c; }
  }
  __syncthreads();

  const int bkt = tid & 127;
  const int seg = tid >> 7;
  int pos = hist[seg * 128 + bkt];
  const int sbase = seg * 1024;
  const int b = bh >> 3, h = bh & 7;
  const size_t stb = (size_t)b * (H_ * S_) + (size_t)h * S_;
  for (int k = 0; k < 1024; ++k) {
    const int t = sbase + k;
    if (lb[t] == bkt) {
      st[stb + pos] = t;
      undo[base + t] = h * S_ + pos;
      ++pos;
    }
  }
}

// ---------------------------------------------------------------------------
// Kernel 3 (REWRITTEN): bucketed attention via f16 MFMA.
// One block per (b, chunk). 64 q x 128 kv x 64 d.
// MFMA layouts (m89/m91/m120-verified): A: m=lane&15, k=quad*8+j (8 contig k)
//                                       C/D: col(n)=lane&15, row(m)=quad*4+reg
// Wave w owns query rows [16w,16w+16): QK jt-tiles 0..7, PV dt-tiles 0..3.
// LDS 36.4 KB -> 4 blocks/CU:
//   sQ: q rows f16 [64][72]      (later vT cols j=64..127)
//   sK: k rows f16 [64][72] x2 stages (later vT cols j=0..63)
//   sP: p [i][j] f16 [64][136]
// ---------------------------------------------------------------------------
__global__ __launch_bounds__(256, 4) void attn_kernel(
    const float* __restrict__ qk, const float* __restrict__ v,
    const int* __restrict__ st, float* __restrict__ so,
    float* __restrict__ slogits)
{
  __shared__ _Float16 sQ[64 * 72];    // 9216 B
  __shared__ _Float16 sK[64 * 72];    // 9216 B
  __shared__ _Float16 sP[64 * 136];   // 17408 B
  __shared__ int sIds[128];

  const int tid = threadIdx.x;
  const int c   = blockIdx.x & (NC_ - 1);
  const int b   = blockIdx.x >> 10;
  const int cm1 = (c + NC_ - 1) & (NC_ - 1);
  const size_t bst = (size_t)b * (H_ * S_);
  const size_t row0 = bst + (size_t)c * 64;     // kv rows 0..63
  const size_t row1 = bst + (size_t)cm1 * 64;   // kv rows 64..127

  const int lane = tid & 63;
  const int w    = tid >> 6;       // wave 0..3
  const int m16  = lane & 15;
  const int qd   = lane >> 4;      // quad 0..3

  if (tid < 128) sIds[tid] = (tid < 64) ? st[row0 + tid] : st[row1 + tid - 64];

  // ---- stage q (raw) + k rows 0..63 (normalized, *D^-0.5) ----
  const int r  = tid >> 2, qu = tid & 3;
  {
    const int tok = st[row0 + r];
    const f32x4* src = (const f32x4*)(qk + ((size_t)b * S_ + tok) * D_ + qu * 16);
    float x[16];
#pragma unroll
    for (int k = 0; k < 4; ++k) ((f32x4*)x)[k] = src[k];
    float ss = 0.f;
#pragma unroll
    for (int k = 0; k < 16; ++k) ss = fmaf(x[k], x[k], ss);
    ss += __shfl_xor(ss, 1); ss += __shfl_xor(ss, 2);
    const float inv = 0.125f / (sqrtf(ss) + 1e-6f);
    f16x8 raw0, raw1, nrm0, nrm1;
#pragma unroll
    for (int jj = 0; jj < 8; ++jj) {
      raw0[jj] = (_Float16)x[jj];         raw1[jj] = (_Float16)x[jj + 8];
      nrm0[jj] = (_Float16)(x[jj] * inv); nrm1[jj] = (_Float16)(x[jj + 8] * inv);
    }
    *(f16x8*)(sQ + r * 72 + qu * 16)     = raw0;
    *(f16x8*)(sQ + r * 72 + qu * 16 + 8) = raw1;
    *(f16x8*)(sK + r * 72 + qu * 16)     = nrm0;
    *(f16x8*)(sK + r * 72 + qu * 16 + 8) = nrm1;
  }
  __syncthreads();                                   // b0: q + k-half0 ready

  // ---- QK^T ----
  f32x4 acc[8];
#pragma unroll
  for (int jt = 0; jt < 8; ++jt) acc[jt] = (f32x4){0.f, 0.f, 0.f, 0.f};

  const _Float16* qrow = sQ + (16 * w + m16) * 72;   // A: m = lane&15
  const f16x8 a0 = *(const f16x8*)(qrow + 8 * qd);          // k = 8*quad + j
  const f16x8 a1 = *(const f16x8*)(qrow + 32 + 8 * qd);

#pragma unroll
  for (int jt = 0; jt < 4; ++jt) {                   // j-tiles 0..3 (kv 0..63)
    const _Float16* krow = sK + (16 * jt + m16) * 72;  // B: n = lane&15
    const f16x8 b0 = *(const f16x8*)(krow + 8 * qd);
    const f16x8 b1 = *(const f16x8*)(krow + 32 + 8 * qd);
    acc[jt] = __builtin_amdgcn_mfma_f32_16x16x32_f16(a0, b0, acc[jt], 0, 0, 0);
    acc[jt] = __builtin_amdgcn_mfma_f32_16x16x32_f16(a1, b1, acc[jt], 0, 0, 0);
  }
  __syncthreads();                                   // b1: k-half0 reads done

  {                                                  // restage k rows 64..127
    const int tok = st[row1 + r];
    const f32x4* src = (const f32x4*)(qk + ((size_t)b * S_ + tok) * D_ + qu * 16);
    float x[16];
#pragma unroll
    for (int k = 0; k < 4; ++k) ((f32x4*)x)[k] = src[k];
    float ss = 0.f;
#pragma unroll
    for (int k = 0; k < 16; ++k) ss = fmaf(x[k], x[k], ss);
    ss += __shfl_xor(ss, 1); ss += __shfl_xor(ss, 2);
    const float inv = 0.125f / (sqrtf(ss) + 1e-6f);
    f16x8 nrm0, nrm1;
#pragma unroll
    for (int jj = 0; jj < 8; ++jj) {
      nrm0[jj] = (_Float16)(x[jj] * inv); nrm1[jj] = (_Float16)(x[jj + 8] * inv);
    }
    *(f16x8*)(sK + r * 72 + qu * 16)     = nrm0;
    *(f16x8*)(sK + r * 72 + qu * 16 + 8) = nrm1;
  }
  __syncthreads();                                   // b2: k-half1 ready

#pragma unroll
  for (int jt = 4; jt < 8; ++jt) {                   // j-tiles 4..7 (kv 64..127)
    const _Float16* krow = sK + (16 * (jt - 4) + m16) * 72;
    const f16x8 b0 = *(const f16x8*)(krow + 8 * qd);
    const f16x8 b1 = *(const f16x8*)(krow + 32 + 8 * qd);
    acc[jt] = __builtin_amdgcn_mfma_f32_16x16x32_f16(a0, b0, acc[jt], 0, 0, 0);
    acc[jt] = __builtin_amdgcn_mfma_f32_16x16x32_f16(a1, b1, acc[jt], 0, 0, 0);
  }

  // ---- issue v gather loads early (consumed after next barrier) ----
  const int jp = tid >> 2;                           // kv row pair 2jp, 2jp+1
  const int tok0 = sIds[2 * jp], tok1 = sIds[2 * jp + 1];
  f32x4 vr0[4], vr1[4];
  {
    const f32x4* s0 = (const f32x4*)(v + ((size_t)b * S_ + tok0) * D_ + qu * 16);
    const f32x4* s1 = (const f32x4*)(v + ((size_t)b * S_ + tok1) * D_ + qu * 16);
#pragma unroll
    for (int k = 0; k < 4; ++k) { vr0[k] = s0[k]; vr1[k] = s1[k]; }
  }

  // ---- self-mask + softmax, all in registers (row i within one 16-lane grp) ----
  int rid[4];
#pragma unroll
  for (int rg = 0; rg < 4; ++rg) rid[rg] = sIds[16 * w + 4 * qd + rg];
  float rmax[4] = {-1e30f, -1e30f, -1e30f, -1e30f};
#pragma unroll
  for (int jt = 0; jt < 8; ++jt) {
    const int cid = sIds[16 * jt + m16];
#pragma unroll
    for (int rg = 0; rg < 4; ++rg) {
      float x = acc[jt][rg];
      if (rid[rg] == cid) x = -5e4f;                 // TOKEN_SELF_ATTN_VALUE
      acc[jt][rg] = x;
      rmax[rg] = fmaxf(rmax[rg], x);
    }
  }
#pragma unroll
  for (int rg = 0; rg < 4; ++rg) {
    rmax[rg] = fmaxf(rmax[rg], __shfl_xor(rmax[rg], 1));
    rmax[rg] = fmaxf(rmax[rg], __shfl_xor(rmax[rg], 2));
    rmax[rg] = fmaxf(rmax[rg], __shfl_xor(rmax[rg], 4));
    rmax[rg] = fmaxf(rmax[rg], __shfl_xor(rmax[rg], 8));
  }
  float rsum[4] = {0.f, 0.f, 0.f, 0.f};
#pragma unroll
  for (int jt = 0; jt < 8; ++jt)
#pragma unroll
    for (int rg = 0; rg < 4; ++rg) {
      const float e = __expf(acc[jt][rg] - rmax[rg]);
      acc[jt][rg] = e;
      rsum[rg] += e;
    }
#pragma unroll
  for (int rg = 0; rg < 4; ++rg) {
    rsum[rg] += __shfl_xor(rsum[rg], 1);
    rsum[rg] += __shfl_xor(rsum[rg], 2);
    rsum[rg] += __shfl_xor(rsum[rg], 4);
    rsum[rg] += __shfl_xor(rsum[rg], 8);
  }
  float rinv[4];
#pragma unroll
  for (int rg = 0; rg < 4; ++rg) rinv[rg] = 1.f / rsum[rg];
  if (m16 == 0) {
#pragma unroll
    for (int rg = 0; rg < 4; ++rg)
      slogits[row0 + 16 * w + 4 * qd + rg] = rmax[rg] + __logf(rsum[rg]);
  }

  // ---- p -> LDS [i][j] f16 (the verified C/D -> A-layout transform) ----
#pragma unroll
  for (int jt = 0; jt < 8; ++jt)
#pragma unroll
    for (int rg = 0; rg < 4; ++rg)
      sP[(16 * w + 4 * qd + rg) * 136 + 16 * jt + m16] = (_Float16)acc[jt][rg];

  __syncthreads();                                   // b3: QK reads of sQ/sK done

  // ---- stage vT: [d][j] f16, j 0..63 -> sK, j 64..127 -> sQ ----
  {
    const int j = 2 * jp;
    _Float16* dst = (j < 64) ? (sK + (j)) : (sQ + (j - 64));
    float x0[16], x1[16];
#pragma unroll
    for (int k = 0; k < 4; ++k) { ((f32x4*)x0)[k] = vr0[k]; ((f32x4*)x1)[k] = vr1[k]; }
#pragma unroll
    for (int jj = 0; jj < 16; ++jj) {
      const int d = qu * 16 + jj;
      f16x2 pk; pk[0] = (_Float16)x0[jj]; pk[1] = (_Float16)x1[jj];
      *(f16x2*)(dst + d * 72) = pk;
    }
  }
  __syncthreads();                                   // b4: p + vT ready

  // ---- PV via MFMA: D[i][d], K-steps over j ----
  f32x4 oacc[4];
#pragma unroll
  for (int dt = 0; dt < 4; ++dt) oacc[dt] = (f32x4){0.f, 0.f, 0.f, 0.f};

  const _Float16* prow = sP + (16 * w + m16) * 136;  // A: m = lane&15 (= i)
#pragma unroll
  for (int s = 0; s < 4; ++s) {                      // j-block 32s
    const f16x8 ap = *(const f16x8*)(prow + 32 * s + 8 * qd);
    const _Float16* vbase = (s < 2) ? sK : sQ;
    const int col0 = 32 * (s & 1) + 8 * qd;
#pragma unroll
    for (int dt = 0; dt < 4; ++dt) {
      const f16x8 bv = *(const f16x8*)(vbase + (16 * dt + m16) * 72 + col0);
      oacc[dt] = __builtin_amdgcn_mfma_f32_16x16x32_f16(ap, bv, oacc[dt], 0, 0, 0);
    }
  }

  // ---- epilogue: normalize rows, store ----
  const size_t ob = row0 * 64;
#pragma unroll
  for (int dt = 0; dt < 4; ++dt)
#pragma unroll
    for (int rg = 0; rg < 4; ++rg) {
      const int i = 16 * w + 4 * qd + rg;            // D row = quad*4+reg
      const int d = 16 * dt + m16;                   // D col = lane&15
      so[ob + (size_t)i * 64 + d] = oacc[dt][rg] * rinv[rg];
    }
}

// ---------------------------------------------------------------------------
// Kernel 4: un-sort + combine rounds with logsumexp weights. Unchanged.
// ---------------------------------------------------------------------------
__global__ __launch_bounds__(256) void combine_kernel(
    const float* __restrict__ so, const float* __restrict__ slogits,
    const int* __restrict__ undo, float* __restrict__ out)
{
  const int gt = blockIdx.x * 4 + (threadIdx.x >> 6);
  const int d  = threadIdx.x & 63;
  const int b  = gt >> 13;
  const int t  = gt & (S_ - 1);
  const size_t bst = (size_t)b * (H_ * S_);

  int p[8]; float l[8];
#pragma unroll
  for (int h = 0; h < 8; ++h) {
    p[h] = undo[((size_t)b * 8 + h) * S_ + t];
    l[h] = slogits[bst + p[h]];
  }
  float m = l[0];
#pragma unroll
  for (int h = 1; h < 8; ++h) m = fmaxf(m, l[h]);
  float wv[8], W = 0.f;
#pragma unroll
  for (int h = 0; h < 8; ++h) { wv[h] = expf(l[h] - m); W += wv[h]; }
  const float iW = 1.f / W;
  float acc = 0.f;
#pragma unroll
  for (int h = 0; h < 8; ++h)
    acc = fmaf(wv[h], so[(bst + (size_t)p[h]) * 64 + d], acc);
  out[(size_t)gt * 64 + d] = acc * iW;
}

// ---------------------------------------------------------------------------
extern "C" void kernel_launch(void* const* d_in, const int* in_sizes, int n_in,
                              void* d_out, int out_size, void* d_ws, size_t ws_size,
                              hipStream_t stream)
{
  const float* qk  = (const float*)d_in[0];
  const float* v   = (const float*)d_in[1];
  const float* rot = (const float*)d_in[2];
  float* out = (float*)d_out;

  char* ws = (char*)d_ws;
  const size_t MB = 1ull << 20;
  int*   bucket = (int*)  (ws + 0 * MB);
  int*   st     = (int*)  (ws + 2 * MB);
  int*   undo   = (int*)  (ws + 4 * MB);
  float* slog   = (float*)(ws + 6 * MB);
  float* so     = (float*)(ws + 8 * MB);
  if (ws_size < 136 * MB) return;

  hipLaunchKernelGGL(hash_kernel,    dim3(64 * 32),     dim3(256),  0, stream, qk, rot, bucket);
  hipLaunchKernelGGL(sort_kernel,    dim3(64),          dim3(1024), 0, stream, bucket, st, undo);
  hipLaunchKernelGGL(attn_kernel,    dim3(B_ * NC_),    dim3(256),  0, stream, qk, v, st, so, slog);
  hipLaunchKernelGGL(combine_kernel, dim3(B_ * S_ / 4), dim3(256),  0, stream, so, slog, undo, out);
}